// Round 7
// baseline (326.325 us; speedup 1.0000x reference)
//
#include <hip/hip_runtime.h>
#include <hip/hip_bf16.h>

#define U_ 2048
#define T_ 512
#define K_ 128
#define B_ 32
#define RHO_ 0.99f
#define CPB 64       // chains per block
#define NTILES 5     // 16-col tiles covering 64+15 cols

typedef __attribute__((ext_vector_type(8))) short short8;
typedef __attribute__((ext_vector_type(4))) float f32x4;

// tanh(x) = 1 - 2/(exp2(2*log2e*x)+1).  v_exp_f32 + v_rcp_f32 (~1ulp each):
// 5 short ops vs __expf + precise-div's ~15 (div-scale/fmas/fixup chain).
__device__ __forceinline__ float fast_tanh(float x) {
  float e = __builtin_amdgcn_exp2f(2.8853900817779268f * x);
  return 1.0f - 2.0f * __builtin_amdgcn_rcpf(e + 1.0f);
}

__device__ __forceinline__ unsigned short bf16_rne(float x) {
  unsigned int u = __float_as_uint(x);
  u += 0x7FFFu + ((u >> 16) & 1u);
  return (unsigned short)(u >> 16);
}

// ---------------- converts ----------------
// A [16384][128] fp32 -> Ab [16384][256] bf16 (k<128: hi, k>=128: lo residual)
__global__ __launch_bounds__(256) void convert_a_kernel(
    const float* __restrict__ A, unsigned short* __restrict__ Ab) {
  const int gi = blockIdx.x * 256 + threadIdx.x;
  const int m = gi >> 5;          // needs 2048 blocks
  const int kq = (gi & 31) << 2;
  const float4 v = *(const float4*)&A[(size_t)m * K_ + kq];
  ushort4 hi, lo;
  hi.x = bf16_rne(v.x); hi.y = bf16_rne(v.y); hi.z = bf16_rne(v.z); hi.w = bf16_rne(v.w);
  lo.x = bf16_rne(v.x - __uint_as_float((unsigned)hi.x << 16));
  lo.y = bf16_rne(v.y - __uint_as_float((unsigned)hi.y << 16));
  lo.z = bf16_rne(v.z - __uint_as_float((unsigned)hi.z << 16));
  lo.w = bf16_rne(v.w - __uint_as_float((unsigned)hi.w << 16));
  *(ushort4*)&Ab[(size_t)m * 256 + kq] = hi;
  *(ushort4*)&Ab[(size_t)m * 256 + 128 + kq] = lo;
}

// W [128][2048] fp32 -> Wbt [2048][256] bf16 transposed, duplicated along k.
__global__ __launch_bounds__(256) void convert_w_kernel(
    const float* __restrict__ W, unsigned short* __restrict__ Wbt) {
  const int gi = blockIdx.x * 256 + threadIdx.x;   // 65536 threads
  const int kq = gi >> 11;        // 0..31
  const int n = gi & 2047;
  const int k = kq << 2;
  ushort4 w;
  w.x = bf16_rne(W[(size_t)(k + 0) * U_ + n]);
  w.y = bf16_rne(W[(size_t)(k + 1) * U_ + n]);
  w.z = bf16_rne(W[(size_t)(k + 2) * U_ + n]);
  w.w = bf16_rne(W[(size_t)(k + 3) * U_ + n]);
  *(ushort4*)&Wbt[(size_t)n * 256 + k] = w;
  *(ushort4*)&Wbt[(size_t)n * 256 + 128 + k] = w;
}

// ---------------- v9: fused GEMM+scan, no W ring, 4 blocks/CU ----------------
// v8 post-mortem: nothing saturated (Mfma 8%, VALU 32%, HBM 21%, occ 21%)
// -> latency/convoy-bound.  v9: (a) drop the 40KB W-LDS ring (Wbt proved
// L2-resident: FETCH 6.4MB) and load B-fragments per-lane from L2 like the
// proven v6 GEMM; LDS 58.9->13.4KB; (b) CPB 64, 1024 blocks,
// launch_bounds(256,4) -> 4 blocks/CU = 16 waves/CU so independent block
// pipelines absorb each other's vmcnt stalls and serial scans; (c) cheap
// tanh (exp2+rcp builtins) removes the precise-div chain from the 512-step
// recurrence (the 32% VALUBusy suspect).
__global__ __launch_bounds__(256, 4) void fused_gemm_scan3_kernel(
    const unsigned short* __restrict__ Ab, const unsigned short* __restrict__ Wbt,
    const float* __restrict__ bias, const float* __restrict__ h0,
    float* __restrict__ out) {
  __shared__ float u_lds[16 * 82];     // 5248 B (stride 82 -> 2-way banks, free)
  __shared__ float bias_lds[U_];       // 8 KB
  const int tid = threadIdx.x;
  // XCD-aware remap: xcd = id&7 owns 4 whole batches -> Ab panel L2-resident.
  const int id = blockIdx.x + (blockIdx.y << 5);   // 0..1023
  const int xcd = id & 7;
  const int wk = id >> 3;                          // 0..127
  const int b = (xcd << 2) + (wk >> 5);            // batch 0..31
  const int bx = wk & 31;                          // chain group (64 chains)
  const int c0 = bx << 6;
  const int cbase = bx << 2;                       // col-tile base (units of 16)
  const int wave = tid >> 6;
  const int lane = tid & 63;
  const int r = lane & 15;
  const int q = lane >> 4;
  const int koff = q << 3;

  #pragma unroll
  for (int i = 0; i < 8; ++i)
    bias_lds[(i << 8) + tid] = bias[(i << 8) + tid];

  const unsigned short* const aBase = Ab + (((size_t)b * T_) << 8);
  short8 af[8];                        // A rows t0+r, 8 k-steps (hi 0-3, lo 4-7)
  #pragma unroll
  for (int ks = 0; ks < 8; ++ks)
    af[ks] = *(const short8*)(aBase + (((size_t)r) << 8) + (ks << 5) + koff);

  float h = 0.0f;
  if (tid < CPB)
    h = h0[((size_t)b << 11) + ((c0 + tid + U_ - 1) & (U_ - 1))];

  __syncthreads();                     // bias_lds ready

  for (int it = 0; it < T_ / 16; ++it) {
    const int t0 = it << 4;

    // ---- B-fragments from Wbt via L2: wave w -> tile w; wave0 also tile 4.
    // 16x16x32 frag for lane (r,q), k-step ks = 16B at row*256+ks*32+q*8.
    short8 bfq[2][4];
    #pragma unroll
    for (int u = 0; u < 2; ++u) {
      const int j = (u == 0) ? wave : 4;
      if (u == 0 || wave == 0) {
        const int n = (((cbase + it + j) & 127) << 4) + r;
        #pragma unroll
        for (int ks = 0; ks < 4; ++ks)
          bfq[u][ks] = *(const short8*)(Wbt + ((size_t)n << 8) + (ks << 5) + koff);
      }
    }

    // ---- MFMA: u-tile [16 t-rows x 80 cols] ----
    f32x4 acc[2];
    #pragma unroll
    for (int u = 0; u < 2; ++u) {
      acc[u] = (f32x4){0.f, 0.f, 0.f, 0.f};
      if (u == 0 || wave == 0) {
        #pragma unroll
        for (int ks = 0; ks < 8; ++ks)   // lo-half reuses same W (dup'd k)
          acc[u] = __builtin_amdgcn_mfma_f32_16x16x32_bf16(af[ks], bfq[u][ks & 3], acc[u], 0, 0, 0);
      }
    }

    __syncthreads();                   // prev scan's u_lds reads retired

    // ---- u + bias -> LDS (D layout: col=lane&15, row=q*4+reg) ----
    #pragma unroll
    for (int u = 0; u < 2; ++u) {
      const int j = (u == 0) ? wave : 4;
      if (u == 0 || wave == 0) {
        const float bv = bias_lds[(c0 + t0 + (j << 4) + r) & (U_ - 1)];
        #pragma unroll
        for (int reg = 0; reg < 4; ++reg)
          u_lds[((q << 2) + reg) * 82 + (j << 4) + r] = acc[u][reg] + bv;
      }
    }

    // ---- prefetch next-iter A frags (latency covered by scan phase) ----
    if (it + 1 < T_ / 16) {
      #pragma unroll
      for (int ks = 0; ks < 8; ++ks)
        af[ks] = *(const short8*)(aBase + (((size_t)(t0 + 16 + r)) << 8) + (ks << 5) + koff);
    }

    __syncthreads();                   // u_lds visible

    // ---- scan: 16 sequential steps on the diagonal (wave 0 only) ----
    if (tid < CPB) {
      float uv[16];
      #pragma unroll
      for (int tt = 0; tt < 16; ++tt)
        uv[tt] = u_lds[tt * 82 + tid + tt];
      float* const orow = out + (((size_t)(b * T_ + t0)) << 11);
      #pragma unroll
      for (int tt = 0; tt < 16; ++tt) {
        h = fast_tanh(fmaf(RHO_, h, uv[tt]));
        __builtin_nontemporal_store(
            h, &orow[((size_t)tt << 11) + ((c0 + tid + t0 + tt) & (U_ - 1))]);
      }
    }
    // waves 1-3 run ahead into next iter's B loads + MFMA (touch only
    // bfq/af), then wait at the first barrier until wave0's scan retires.
  }
}

// ---------------- fallback path (R1, proven correct) ----------------
__global__ __launch_bounds__(256) void ring_scan_kernel(
    float* __restrict__ buf, const float* __restrict__ h0) {
  const int b = blockIdx.y;
  const int c = (blockIdx.x << 8) + threadIdx.x;
  float* const base = buf + (size_t)b * (T_ * U_);
  float h = h0[((size_t)b << 11) + ((c + U_ - 1) & (U_ - 1))];
  float wA[8], wB[8];
  #pragma unroll
  for (int j = 0; j < 8; ++j)
    wA[j] = base[((size_t)j << 11) + ((c + j) & (U_ - 1))];
  for (int t0 = 0; t0 < T_; t0 += 16) {
    #pragma unroll
    for (int j = 0; j < 8; ++j) {
      const int t = t0 + 8 + j;
      wB[j] = base[((size_t)t << 11) + ((c + t) & (U_ - 1))];
    }
    #pragma unroll
    for (int j = 0; j < 8; ++j) {
      const int t = t0 + j;
      h = fast_tanh(fmaf(RHO_, h, wA[j]));
      base[((size_t)t << 11) + ((c + t) & (U_ - 1))] = h;
    }
    if (t0 + 16 < T_) {
      #pragma unroll
      for (int j = 0; j < 8; ++j) {
        const int t = t0 + 16 + j;
        wA[j] = base[((size_t)t << 11) + ((c + t) & (U_ - 1))];
      }
    }
    #pragma unroll
    for (int j = 0; j < 8; ++j) {
      const int t = t0 + 8 + j;
      h = fast_tanh(fmaf(RHO_, h, wB[j]));
      base[((size_t)t << 11) + ((c + t) & (U_ - 1))] = h;
    }
  }
}

__global__ __launch_bounds__(256, 4) void gemm_bias_kernel(
    const float* __restrict__ A, const float* __restrict__ W,
    const float* __restrict__ bias, float* __restrict__ out) {
  __shared__ float Asf[64][68];
  __shared__ float Bsf[64][64];
  const int tid = threadIdx.x;
  const int m0 = blockIdx.y << 6;
  const int n0 = blockIdx.x << 6;
  const int tx = tid & 15;
  const int ty = tid >> 4;
  float acc[4][4] = {};
  #pragma unroll
  for (int kb = 0; kb < 2; ++kb) {
    if (kb) __syncthreads();
    {
      const int c4 = tid & 15;
      const int r0 = tid >> 4;
      #pragma unroll
      for (int rr = 0; rr < 4; ++rr) {
        const int r = r0 + (rr << 4);
        const float4 v = *(const float4*)(A + (size_t)(m0 + r) * K_ + (kb << 6) + (c4 << 2));
        Asf[(c4 << 2) + 0][r] = v.x;
        Asf[(c4 << 2) + 1][r] = v.y;
        Asf[(c4 << 2) + 2][r] = v.z;
        Asf[(c4 << 2) + 3][r] = v.w;
      }
    }
    {
      const int c4 = tid & 15;
      const int r0 = tid >> 4;
      #pragma unroll
      for (int rr = 0; rr < 4; ++rr) {
        const int k = r0 + (rr << 4);
        *(float4*)&Bsf[k][c4 << 2] =
            *(const float4*)(W + (size_t)((kb << 6) + k) * U_ + n0 + (c4 << 2));
      }
    }
    __syncthreads();
    #pragma unroll 16
    for (int k = 0; k < 64; ++k) {
      const float4 a = *(const float4*)&Asf[k][ty << 2];
      const float4 b = *(const float4*)&Bsf[k][tx << 2];
      acc[0][0] = fmaf(a.x, b.x, acc[0][0]); acc[0][1] = fmaf(a.x, b.y, acc[0][1]);
      acc[0][2] = fmaf(a.x, b.z, acc[0][2]); acc[0][3] = fmaf(a.x, b.w, acc[0][3]);
      acc[1][0] = fmaf(a.y, b.x, acc[1][0]); acc[1][1] = fmaf(a.y, b.y, acc[1][1]);
      acc[1][2] = fmaf(a.y, b.z, acc[1][2]); acc[1][3] = fmaf(a.y, b.w, acc[1][3]);
      acc[2][0] = fmaf(a.z, b.x, acc[2][0]); acc[2][1] = fmaf(a.z, b.y, acc[2][1]);
      acc[2][2] = fmaf(a.z, b.z, acc[2][2]); acc[2][3] = fmaf(a.z, b.w, acc[2][3]);
      acc[3][0] = fmaf(a.w, b.x, acc[3][0]); acc[3][1] = fmaf(a.w, b.y, acc[3][1]);
      acc[3][2] = fmaf(a.w, b.z, acc[3][2]); acc[3][3] = fmaf(a.w, b.w, acc[3][3]);
    }
  }
  const float4 bv = *(const float4*)(bias + n0 + (tx << 2));
  #pragma unroll
  for (int i = 0; i < 4; ++i) {
    float4 o;
    o.x = acc[i][0] + bv.x; o.y = acc[i][1] + bv.y;
    o.z = acc[i][2] + bv.z; o.w = acc[i][3] + bv.w;
    *(float4*)(out + (size_t)(m0 + (ty << 2) + i) * U_ + n0 + (tx << 2)) = o;
  }
}

extern "C" void kernel_launch(void* const* d_in, const int* in_sizes, int n_in,
                              void* d_out, int out_size, void* d_ws, size_t ws_size,
                              hipStream_t stream) {
  const float* A    = (const float*)d_in[0];   // inputs [B,T,D_IN]
  const float* h0   = (const float*)d_in[1];   // [B,U]
  const float* W    = (const float*)d_in[2];   // kernel [D_IN,U]
  const float* bias = (const float*)d_in[3];   // [U]
  float* out = (float*)d_out;                  // [B,T,U]

  const size_t AB_BYTES = (size_t)B_ * T_ * 256 * 2;         // 8,388,608
  const size_t WB_BYTES = (size_t)U_ * 256 * 2;              // 1,048,576
  const size_t NEEDED = AB_BYTES + WB_BYTES;

  if (ws_size >= NEEDED) {
    unsigned short* Ab  = (unsigned short*)d_ws;
    unsigned short* Wbt = (unsigned short*)((char*)d_ws + AB_BYTES);

    convert_a_kernel<<<2048, 256, 0, stream>>>(A, Ab);
    convert_w_kernel<<<256, 256, 0, stream>>>(W, Wbt);
    dim3 fg(U_ / CPB, B_);              // (32, 32) = 1024 blocks
    fused_gemm_scan3_kernel<<<fg, 256, 0, stream>>>(Ab, Wbt, bias, h0, out);
  } else {
    dim3 gemm_grid(U_ / 64, (B_ * T_) / 64);
    gemm_bias_kernel<<<gemm_grid, 256, 0, stream>>>(A, W, bias, out);
    dim3 scan_grid(U_ / 256, B_);       // (8, 32)
    ring_scan_kernel<<<scan_grid, 256, 0, stream>>>(out, h0);
  }
}

// Round 8
// 192.688 us; speedup vs baseline: 1.6935x; 1.6935x over previous
//
#include <hip/hip_runtime.h>
#include <hip/hip_bf16.h>

#define U_ 2048
#define T_ 512
#define K_ 128
#define B_ 32
#define RHO_ 0.99f
#define CPB 128      // chains per block
#define NTILES 9     // 16-col tiles covering 128+15 cols
#define NSLOTS 10    // W ring slots (1 spare staged ahead)

typedef __attribute__((ext_vector_type(8))) short short8;
typedef __attribute__((ext_vector_type(4))) float f32x4;

// tanh(x) = 1 - 2/(exp2(2*log2e*x)+1): v_exp_f32 + v_rcp_f32, ~5 ops,
// correct +/-1 saturation for |x| large.  Refcheck-proven in v9.
__device__ __forceinline__ float fast_tanh(float x) {
  float e = __builtin_amdgcn_exp2f(2.8853900817779268f * x);
  return 1.0f - 2.0f * __builtin_amdgcn_rcpf(e + 1.0f);
}

__device__ __forceinline__ unsigned short bf16_rne(float x) {
  unsigned int u = __float_as_uint(x);
  u += 0x7FFFu + ((u >> 16) & 1u);
  return (unsigned short)(u >> 16);
}

#define GLOAD_LDS16(gsrc, ldst)                                        \
  __builtin_amdgcn_global_load_lds(                                    \
      (const __attribute__((address_space(1))) void*)(gsrc),           \
      (__attribute__((address_space(3))) void*)(ldst), 16, 0, 0)

// ---------------- converts ----------------
// A [16384][128] fp32 -> Ab [16384][256] bf16 (k<128: hi, k>=128: lo residual)
__global__ __launch_bounds__(256) void convert_a_kernel(
    const float* __restrict__ A, unsigned short* __restrict__ Ab) {
  const int gi = blockIdx.x * 256 + threadIdx.x;
  const int m = gi >> 5;          // needs 2048 blocks
  const int kq = (gi & 31) << 2;
  const float4 v = *(const float4*)&A[(size_t)m * K_ + kq];
  ushort4 hi, lo;
  hi.x = bf16_rne(v.x); hi.y = bf16_rne(v.y); hi.z = bf16_rne(v.z); hi.w = bf16_rne(v.w);
  lo.x = bf16_rne(v.x - __uint_as_float((unsigned)hi.x << 16));
  lo.y = bf16_rne(v.y - __uint_as_float((unsigned)hi.y << 16));
  lo.z = bf16_rne(v.z - __uint_as_float((unsigned)hi.z << 16));
  lo.w = bf16_rne(v.w - __uint_as_float((unsigned)hi.w << 16));
  *(ushort4*)&Ab[(size_t)m * 256 + kq] = hi;
  *(ushort4*)&Ab[(size_t)m * 256 + 128 + kq] = lo;
}

// W [128][2048] fp32 -> Wbt [2048][256] bf16 transposed, duplicated along k.
__global__ __launch_bounds__(256) void convert_w_kernel(
    const float* __restrict__ W, unsigned short* __restrict__ Wbt) {
  const int gi = blockIdx.x * 256 + threadIdx.x;   // 65536 threads
  const int kq = gi >> 11;        // 0..31
  const int n = gi & 2047;
  const int k = kq << 2;
  ushort4 w;
  w.x = bf16_rne(W[(size_t)(k + 0) * U_ + n]);
  w.y = bf16_rne(W[(size_t)(k + 1) * U_ + n]);
  w.z = bf16_rne(W[(size_t)(k + 2) * U_ + n]);
  w.w = bf16_rne(W[(size_t)(k + 3) * U_ + n]);
  *(ushort4*)&Wbt[(size_t)n * 256 + k] = w;
  *(ushort4*)&Wbt[(size_t)n * 256 + 128 + k] = w;
}

// -------- v10: fused GEMM+scan, global_load_lds staging, 1 barrier/iter -----
// v8 base (proven 94us) with the two exposed vmcnt(0) drains removed:
//  * A-tile (16 rows x 512B, dbuf) + W-ring slot staged by global_load_lds
//    issued at the TOP of the iteration -> drained at the single barrier
//    ~400cy later, covered by ds_read+MFMA+u-write.
//  * u_lds double-buffered -> barrier between u-write and scan deleted.
//  * XOR-involution layouts (physical granule p holds logical p^(row&7)):
//    global_load_lds writes linearly, so the SOURCE address is pre-swizzled
//    and the ds_read applies the same XOR (ERRATA-21 both-sides rule).
//    Fragment ds_reads then spread 8 lanes/4-bank-group: conflict-free.
//  * A loaded once per block-iter (8KB) instead of per-wave (32KB).
//  * cheap tanh (exp2+rcp, refcheck-proven), rolling bias in regs.
__global__ __launch_bounds__(256, 2) void fused_gemm_scan4_kernel(
    const unsigned short* __restrict__ Ab, const unsigned short* __restrict__ Wbt,
    const float* __restrict__ bias, const float* __restrict__ h0,
    float* __restrict__ out) {
  __shared__ unsigned short Wl[NSLOTS * 2048];   // 40 KB: 10 slots x 16n x 128k
  __shared__ unsigned short Al[2][4096];         // 16 KB: 2 x 16t x 256k
  __shared__ float u_lds[2][16 * 146];           // 18.25 KB
  const int tid = threadIdx.x;
  // XCD-aware remap: xcd = id&7 owns 4 whole batches -> Ab panel L2-resident.
  const int id = blockIdx.x + (blockIdx.y << 4);   // 0..511
  const int xcd = id & 7;
  const int wk = id >> 3;                          // 0..63
  const int b = (xcd << 2) + (wk >> 4);            // batch 0..31
  const int bx = wk & 15;                          // chain group 0..15
  const int c0 = bx << 7;
  const int cbase = bx << 3;                       // col-tile base (16-col units)
  const int wave = tid >> 6;
  const int lane = tid & 63;
  const int r = lane & 15;
  const int q = lane >> 4;

  // staging index precompute (granule = 16B)
  const int wrow = tid >> 4;                       // W: row 0..15 in slot
  const int wlg  = (tid & 15) ^ (wrow & 7);        // W: logical granule (k<128)
  const int arow0 = tid >> 5;                      // A: rows 0..7  (granule tid)
  const int alg0  = (tid & 31) ^ (arow0 & 7);
  const int arow1 = 8 + arow0;                     // A: rows 8..15 (granule tid+256)
  const int alg1  = (tid & 31) ^ (arow1 & 7);

  const unsigned short* const aBase = Ab + (((size_t)b * T_) << 8);

  // ---- prologue: stage A tile 0, W slots 0..8, bias regs, h ----
  GLOAD_LDS16(aBase + (((size_t)arow0) << 8) + (alg0 << 3), &Al[0][tid << 3]);
  GLOAD_LDS16(aBase + (((size_t)arow1) << 8) + (alg1 << 3), &Al[0][(tid + 256) << 3]);
  #pragma unroll
  for (int j = 0; j < NTILES; ++j) {
    const int g = (cbase + j) & 127;
    GLOAD_LDS16(Wbt + (((size_t)((g << 4) + wrow)) << 8) + (wlg << 3),
                &Wl[(j << 11) + (tid << 3)]);
  }
  float bv[3], nbv[3];
  bv[0] = bias[(c0 + (wave << 4) + r) & (U_ - 1)];
  bv[1] = bias[(c0 + ((wave + 4) << 4) + r) & (U_ - 1)];
  bv[2] = (wave == 0) ? bias[(c0 + 128 + r) & (U_ - 1)] : 0.0f;
  float h = 0.0f;
  if (tid < CPB)
    h = h0[((size_t)b << 11) + ((c0 + tid + U_ - 1) & (U_ - 1))];

  __syncthreads();                     // drains all prologue stages (vmcnt)

  for (int it = 0; it < T_ / 16; ++it) {
    const int cur = it & 1;
    const int t0 = it << 4;

    // ---- step 1: issue next-iter stages (drain covered by MFMA+u-write) ----
    if (it + 1 < T_ / 16) {
      GLOAD_LDS16(aBase + (((size_t)(t0 + 16 + arow0)) << 8) + (alg0 << 3),
                  &Al[cur ^ 1][tid << 3]);
      GLOAD_LDS16(aBase + (((size_t)(t0 + 16 + arow1)) << 8) + (alg1 << 3),
                  &Al[cur ^ 1][(tid + 256) << 3]);
      const int g = (cbase + it + NTILES) & 127;
      GLOAD_LDS16(Wbt + (((size_t)((g << 4) + wrow)) << 8) + (wlg << 3),
                  &Wl[(((it + NTILES) % NSLOTS) << 11) + (tid << 3)]);
      nbv[0] = bias[(c0 + t0 + 16 + (wave << 4) + r) & (U_ - 1)];
      nbv[1] = bias[(c0 + t0 + 16 + ((wave + 4) << 4) + r) & (U_ - 1)];
      if (wave == 0) nbv[2] = bias[(c0 + t0 + 16 + 128 + r) & (U_ - 1)];
    }

    // ---- step 2: fragments from LDS + MFMA ----
    short8 af[8];
    #pragma unroll
    for (int ks = 0; ks < 8; ++ks)
      af[ks] = *(const short8*)&Al[cur][(r << 8) + ((((ks << 2) + q) ^ (r & 7)) << 3)];

    #pragma unroll
    for (int u = 0; u < 3; ++u) {
      const int j = (u < 2) ? (wave + (u << 2)) : 8;
      if (u < 2 || wave == 0) {
        const int slot = (it + j) % NSLOTS;
        short8 bfk[4];
        #pragma unroll
        for (int ks = 0; ks < 4; ++ks)
          bfk[ks] = *(const short8*)&Wl[(slot << 11) + (r << 7) +
                                        ((((ks << 2) + q) ^ (r & 7)) << 3)];
        f32x4 acc = (f32x4){0.f, 0.f, 0.f, 0.f};
        #pragma unroll
        for (int ks = 0; ks < 8; ++ks)   // lo-half reuses same W (dup'd k)
          acc = __builtin_amdgcn_mfma_f32_16x16x32_bf16(af[ks], bfk[ks & 3], acc, 0, 0, 0);
        // ---- step 3: u + bias -> u_lds[cur] (D: col=lane&15, row=q*4+reg) ----
        #pragma unroll
        for (int reg = 0; reg < 4; ++reg)
          u_lds[cur][((q << 2) + reg) * 146 + (j << 4) + r] = acc[reg] + bv[u];
      }
    }

    __syncthreads();                   // single drain point: stages + u_lds

    // ---- step 4: scan 16 sequential steps on the diagonal (waves 0-1) ----
    if (tid < CPB) {
      float uv[16];
      #pragma unroll
      for (int tt = 0; tt < 16; ++tt)
        uv[tt] = u_lds[cur][tt * 146 + tid + tt];
      float* const orow = out + (((size_t)(b * T_ + t0)) << 11);
      #pragma unroll
      for (int tt = 0; tt < 16; ++tt) {
        h = fast_tanh(fmaf(RHO_, h, uv[tt]));
        __builtin_nontemporal_store(
            h, &orow[((size_t)tt << 11) + ((c0 + tid + t0 + tt) & (U_ - 1))]);
      }
    }
    // waves 2-3 run ahead into iter it+1 (stages into Al[cur]/slot it%10 are
    // safe: all iter-it reads retired before barrier(it); they park at
    // barrier(it+1) until the scan waves catch up -> max lead = 1 iter.
    bv[0] = nbv[0]; bv[1] = nbv[1]; bv[2] = nbv[2];
  }
}

// ---------------- fallback path (R1, proven correct) ----------------
__global__ __launch_bounds__(256) void ring_scan_kernel(
    float* __restrict__ buf, const float* __restrict__ h0) {
  const int b = blockIdx.y;
  const int c = (blockIdx.x << 8) + threadIdx.x;
  float* const base = buf + (size_t)b * (T_ * U_);
  float h = h0[((size_t)b << 11) + ((c + U_ - 1) & (U_ - 1))];
  float wA[8], wB[8];
  #pragma unroll
  for (int j = 0; j < 8; ++j)
    wA[j] = base[((size_t)j << 11) + ((c + j) & (U_ - 1))];
  for (int t0 = 0; t0 < T_; t0 += 16) {
    #pragma unroll
    for (int j = 0; j < 8; ++j) {
      const int t = t0 + 8 + j;
      wB[j] = base[((size_t)t << 11) + ((c + t) & (U_ - 1))];
    }
    #pragma unroll
    for (int j = 0; j < 8; ++j) {
      const int t = t0 + j;
      h = fast_tanh(fmaf(RHO_, h, wA[j]));
      base[((size_t)t << 11) + ((c + t) & (U_ - 1))] = h;
    }
    if (t0 + 16 < T_) {
      #pragma unroll
      for (int j = 0; j < 8; ++j) {
        const int t = t0 + 16 + j;
        wA[j] = base[((size_t)t << 11) + ((c + t) & (U_ - 1))];
      }
    }
    #pragma unroll
    for (int j = 0; j < 8; ++j) {
      const int t = t0 + 8 + j;
      h = fast_tanh(fmaf(RHO_, h, wB[j]));
      base[((size_t)t << 11) + ((c + t) & (U_ - 1))] = h;
    }
  }
}

__global__ __launch_bounds__(256, 4) void gemm_bias_kernel(
    const float* __restrict__ A, const float* __restrict__ W,
    const float* __restrict__ bias, float* __restrict__ out) {
  __shared__ float Asf[64][68];
  __shared__ float Bsf[64][64];
  const int tid = threadIdx.x;
  const int m0 = blockIdx.y << 6;
  const int n0 = blockIdx.x << 6;
  const int tx = tid & 15;
  const int ty = tid >> 4;
  float acc[4][4] = {};
  #pragma unroll
  for (int kb = 0; kb < 2; ++kb) {
    if (kb) __syncthreads();
    {
      const int c4 = tid & 15;
      const int r0 = tid >> 4;
      #pragma unroll
      for (int rr = 0; rr < 4; ++rr) {
        const int r = r0 + (rr << 4);
        const float4 v = *(const float4*)(A + (size_t)(m0 + r) * K_ + (kb << 6) + (c4 << 2));
        Asf[(c4 << 2) + 0][r] = v.x;
        Asf[(c4 << 2) + 1][r] = v.y;
        Asf[(c4 << 2) + 2][r] = v.z;
        Asf[(c4 << 2) + 3][r] = v.w;
      }
    }
    {
      const int c4 = tid & 15;
      const int r0 = tid >> 4;
      #pragma unroll
      for (int rr = 0; rr < 4; ++rr) {
        const int k = r0 + (rr << 4);
        *(float4*)&Bsf[k][c4 << 2] =
            *(const float4*)(W + (size_t)((kb << 6) + k) * U_ + n0 + (c4 << 2));
      }
    }
    __syncthreads();
    #pragma unroll 16
    for (int k = 0; k < 64; ++k) {
      const float4 a = *(const float4*)&Asf[k][ty << 2];
      const float4 b = *(const float4*)&Bsf[k][tx << 2];
      acc[0][0] = fmaf(a.x, b.x, acc[0][0]); acc[0][1] = fmaf(a.x, b.y, acc[0][1]);
      acc[0][2] = fmaf(a.x, b.z, acc[0][2]); acc[0][3] = fmaf(a.x, b.w, acc[0][3]);
      acc[1][0] = fmaf(a.y, b.x, acc[1][0]); acc[1][1] = fmaf(a.y, b.y, acc[1][1]);
      acc[1][2] = fmaf(a.y, b.z, acc[1][2]); acc[1][3] = fmaf(a.y, b.w, acc[1][3]);
      acc[2][0] = fmaf(a.z, b.x, acc[2][0]); acc[2][1] = fmaf(a.z, b.y, acc[2][1]);
      acc[2][2] = fmaf(a.z, b.z, acc[2][2]); acc[2][3] = fmaf(a.z, b.w, acc[2][3]);
      acc[3][0] = fmaf(a.w, b.x, acc[3][0]); acc[3][1] = fmaf(a.w, b.y, acc[3][1]);
      acc[3][2] = fmaf(a.w, b.z, acc[3][2]); acc[3][3] = fmaf(a.w, b.w, acc[3][3]);
    }
  }
  const float4 bv = *(const float4*)(bias + n0 + (tx << 2));
  #pragma unroll
  for (int i = 0; i < 4; ++i) {
    float4 o;
    o.x = acc[i][0] + bv.x; o.y = acc[i][1] + bv.y;
    o.z = acc[i][2] + bv.z; o.w = acc[i][3] + bv.w;
    *(float4*)(out + (size_t)(m0 + (ty << 2) + i) * U_ + n0 + (tx << 2)) = o;
  }
}

extern "C" void kernel_launch(void* const* d_in, const int* in_sizes, int n_in,
                              void* d_out, int out_size, void* d_ws, size_t ws_size,
                              hipStream_t stream) {
  const float* A    = (const float*)d_in[0];   // inputs [B,T,D_IN]
  const float* h0   = (const float*)d_in[1];   // [B,U]
  const float* W    = (const float*)d_in[2];   // kernel [D_IN,U]
  const float* bias = (const float*)d_in[3];   // [U]
  float* out = (float*)d_out;                  // [B,T,U]

  const size_t AB_BYTES = (size_t)B_ * T_ * 256 * 2;         // 8,388,608
  const size_t WB_BYTES = (size_t)U_ * 256 * 2;              // 1,048,576
  const size_t NEEDED = AB_BYTES + WB_BYTES;

  if (ws_size >= NEEDED) {
    unsigned short* Ab  = (unsigned short*)d_ws;
    unsigned short* Wbt = (unsigned short*)((char*)d_ws + AB_BYTES);

    convert_a_kernel<<<2048, 256, 0, stream>>>(A, Ab);
    convert_w_kernel<<<256, 256, 0, stream>>>(W, Wbt);
    dim3 fg(U_ / CPB, B_);              // (16, 32) = 512 blocks
    fused_gemm_scan4_kernel<<<fg, 256, 0, stream>>>(Ab, Wbt, bias, h0, out);
  } else {
    dim3 gemm_grid(U_ / 64, (B_ * T_) / 64);
    gemm_bias_kernel<<<gemm_grid, 256, 0, stream>>>(A, W, bias, out);
    dim3 scan_grid(U_ / 256, B_);       // (8, 32)
    ring_scan_kernel<<<scan_grid, 256, 0, stream>>>(out, h0);
  }
}